// Round 19
// baseline (64.445 us; speedup 1.0000x reference)
//
#include <hip/hip_runtime.h>
#include <hip/hip_fp16.h>

// vol:  [B=8, D=64, H=128, W=128, C=2] f32
// flow: [B, D, H, W, 3] f32 (displacements)
// out:  [B, D, H, W, C] f32
//
// R19 = R18 (16-slot one-barrier window, slot = plane & 15) + packed-half2
// trilinear combine: corners stay as half2(x,y); lerp tree in v_pk_* fp16
// (7 sub + 7 fma) replaces 16 cvt + ~23 f32 ops. Cuts each voxel's serial
// VALU chain ~2x (the round-18-identified latency term).
//  - 256 persistent blocks (8b x 32 h-tiles) x 1024 thr; 16 d-tile iters.
//  - LDS: 16 slots x 12 rows x 130 uints (uint = half2(x,y)) = 99,840 B.
//  - gather: 4 x ds_read2_b32 per voxel.
//  - staging: reg-prefetch at TOP of iter; ds_write after gather; ONE
//    barrier per iter (slot-residue disjointness proof in R18 comments).
//  - |jitter| > halo (P~1e-4): exec-masked exact f32 global fallback.

typedef float f32x4 __attribute__((ext_vector_type(4)));
typedef f32x4 __attribute__((aligned(8))) f32x4a;

#define ROWU   130                 // uints per row (128 data + 2 pad)
#define SLOTU  (12 * ROWU)         // 1560 uints per plane-slot
#define NSLOT  16

__device__ __forceinline__ void sample_store(
    const float* __restrict__ vb, const uint* lds_u,
    float f0, float f1, float f2,
    int d, int h, int w, int dbase, int hbase,
    float* __restrict__ out, size_t vox)
{
    float cd = fminf(fmaxf((float)d + f0, 0.0f), 63.0f);
    float ch = fminf(fmaxf((float)h + f1, 0.0f), 127.0f);
    float cw = fminf(fmaxf((float)w + f2, 0.0f), 127.0f);
    int ld = (int)cd; ld = (ld > 62) ? 62 : ld;
    int lh = (int)ch; lh = (lh > 126) ? 126 : lh;
    int lw = (int)cw; lw = (lw > 126) ? 126 : lw;
    const float wd = cd - (float)ld;
    const float wh = ch - (float)lh;
    const float ww = cw - (float)lw;
    const int i_d = ld - dbase;   // LDS path: <= 10 (ld+1 in window)
    const int i_h = lh - hbase;   // <= 10

    float ox, oy;
    if (__builtin_expect(((unsigned)i_d <= 10u) & ((unsigned)i_h <= 10u), 1)) {
        const int m0 = ld & 15;            // slot = plane mod 16
        const int m1 = (ld + 1) & 15;
        const int e0 = m0 * SLOTU + i_h * ROWU + lw;
        const int e1 = m1 * SLOTU + i_h * ROWU + lw;
        const uint uA0 = lds_u[e0],        uA1 = lds_u[e0 + 1];        // read2
        const uint uB0 = lds_u[e0 + ROWU], uB1 = lds_u[e0 + ROWU + 1]; // read2
        const uint uC0 = lds_u[e1],        uC1 = lds_u[e1 + 1];        // read2
        const uint uD0 = lds_u[e1 + ROWU], uD1 = lds_u[e1 + ROWU + 1]; // read2

        const __half2 cA0 = *(const __half2*)&uA0, cA1 = *(const __half2*)&uA1;
        const __half2 cB0 = *(const __half2*)&uB0, cB1 = *(const __half2*)&uB1;
        const __half2 cC0 = *(const __half2*)&uC0, cC1 = *(const __half2*)&uC1;
        const __half2 cD0 = *(const __half2*)&uD0, cD1 = *(const __half2*)&uD1;

        const __half2 ww2 = __float2half2_rn(ww);
        const __half2 wh2 = __float2half2_rn(wh);
        const __half2 wd2 = __float2half2_rn(wd);

        // w-lerp (4), h-lerp (2), d-lerp (1): v0 + w*(v1 - v0), packed (x,y)
        const __half2 a  = __hfma2(ww2, __hsub2(cA1, cA0), cA0);  // (ld  ,lh  )
        const __half2 bq = __hfma2(ww2, __hsub2(cB1, cB0), cB0);  // (ld  ,lh+1)
        const __half2 c  = __hfma2(ww2, __hsub2(cC1, cC0), cC0);  // (ld+1,lh  )
        const __half2 dq = __hfma2(ww2, __hsub2(cD1, cD0), cD0);  // (ld+1,lh+1)
        const __half2 ab = __hfma2(wh2, __hsub2(bq, a), a);
        const __half2 cd2= __hfma2(wh2, __hsub2(dq, c), c);
        const __half2 r  = __hfma2(wd2, __hsub2(cd2, ab), ab);
        ox = __low2float(r);
        oy = __high2float(r);
    } else {
        // exact f32 fallback (rare): lerp tree on global f32 corners
        const int o = (ld << 15) + (lh << 8) + (lw << 1);
        const f32x4 a00 = *(const f32x4a*)(vb + o);
        const f32x4 a01 = *(const f32x4a*)(vb + o + 256);
        const f32x4 a10 = *(const f32x4a*)(vb + o + 32768);
        const f32x4 a11 = *(const f32x4a*)(vb + o + 33024);
        const float xa = a00.x + ww * (a00.z - a00.x);
        const float ya = a00.y + ww * (a00.w - a00.y);
        const float xb = a01.x + ww * (a01.z - a01.x);
        const float yb = a01.y + ww * (a01.w - a01.y);
        const float xc = a10.x + ww * (a10.z - a10.x);
        const float yc = a10.y + ww * (a10.w - a10.y);
        const float xd = a11.x + ww * (a11.z - a11.x);
        const float yd = a11.y + ww * (a11.w - a11.y);
        const float xab = xa + wh * (xb - xa), yab = ya + wh * (yb - ya);
        const float xcd = xc + wh * (xd - xc), ycd = yc + wh * (yd - yc);
        ox = xab + wd * (xcd - xab);
        oy = yab + wd * (ycd - yab);
    }

    *(float2*)(out + vox * 2) = make_float2(ox, oy);
}

__global__ __launch_bounds__(1024, 4) void st_pk_kernel(
    const float* __restrict__ vol,
    const float* __restrict__ flow,
    float* __restrict__ out)
{
    __shared__ uint lds_u[NSLOT * SLOTU];   // 99,840 B (1 block/CU)

    const int t   = threadIdx.x;
    const int bid = blockIdx.x;             // b*32 + htile
    const int h0    = (bid & 31) << 2;
    const int b     = bid >> 5;
    const int hbase = h0 - 4;

    const float* vb = vol + ((size_t)b << 21);

    const int lane = t & 63;
    const int wid  = t >> 6;        // 0..15
    const int dr   = wid >> 2;      // 0..3: d offset within tile
    const int hh   = h0 + (wid & 3);

    // ---- initial stage: planes -4..7 -> slots (plane&15) = (i_d+12)&15 ----
    {
#pragma unroll
        for (int j = 0; j < 9; ++j) {
            const int c   = t + (j << 10);         // 0..9215
            const int s   = c >> 6, q = c & 63;    // row-slot, 16B chunk
            const int i_d = s / 12, i_h = s - i_d * 12;
            const int gd  = max(i_d - 4, 0);
            const int gh  = min(max(hbase + i_h, 0), 127);
            const f32x4 v = *(const f32x4*)(vb + ((((size_t)gd << 7) + gh) << 8) + (q << 2));
            const int sl  = (i_d + 12) & 15;       // plane (i_d-4) mod 16
            const __half2 ha = __floats2half2_rn(v.x, v.y);
            const __half2 hb = __floats2half2_rn(v.z, v.w);
            uint2 pk; pk.x = *(const uint*)&ha; pk.y = *(const uint*)&hb;
            *(uint2*)&lds_u[sl * SLOTU + i_h * ROWU + (q << 1)] = pk;
        }
    }

    // prologue flow (dt=0)
    float cfA0, cfA1, cfA2, cfB0, cfB1, cfB2;
    {
        const size_t rowbase = ((((size_t)((b << 6) | dr) << 7) | hh) << 7);
        const float* fA = flow + (rowbase + lane) * 3;
        cfA0 = fA[0]; cfA1 = fA[1]; cfA2 = fA[2];
        const float* fB = flow + (rowbase + lane + 64) * 3;
        cfB0 = fB[0]; cfB1 = fB[1]; cfB2 = fB[2];
    }
    __syncthreads();

    for (int dt = 0; dt < 16; ++dt) {
        const int d0    = dt << 2;
        const int dbase = d0 - 4;
        const int d     = d0 + dr;
        const size_t rowbase = ((((size_t)((b << 6) | d) << 7) | hh) << 7);
        const size_t voxA = rowbase + lane;

        // ---- prefetch next-iter staging (3 f32x4) + flow (6 f32) ----
        f32x4 s0, s1, s2;
        int   le0 = 0, le1 = 0, le2 = 0;
        float nfA0, nfA1, nfA2, nfB0, nfB1, nfB2;
        if (dt < 15) {
#define ISSUE_ST(K, VV, EE)                                                      \
            {                                                                    \
                const int c = t + ((K) << 10);                                   \
                const int row = c >> 6, q = c & 63;                              \
                const int i_d4 = row / 12, i_h = row - i_d4 * 12;                \
                const int p  = d0 + 8 + i_d4;      /* new planes d0+8..d0+11 */  \
                const int gd = (p > 63) ? 63 : p;                                \
                const int gh = min(max(hbase + i_h, 0), 127);                    \
                VV = *(const f32x4*)(vb + ((((size_t)gd << 7) + gh) << 8) + (q << 2)); \
                EE = (p & 15) * SLOTU + i_h * ROWU + (q << 1);                   \
            }
            ISSUE_ST(0, s0, le0) ISSUE_ST(1, s1, le1) ISSUE_ST(2, s2, le2)
#undef ISSUE_ST
            const int dn = d + 4;
            const size_t rbn = ((((size_t)((b << 6) | dn) << 7) | hh) << 7);
            const float* fA = flow + (rbn + lane) * 3;
            nfA0 = fA[0]; nfA1 = fA[1]; nfA2 = fA[2];
            const float* fB = flow + (rbn + lane + 64) * 3;
            nfB0 = fB[0]; nfB1 = fB[1]; nfB2 = fB[2];
            __builtin_amdgcn_sched_barrier(0);   // pin prefetch above gather
        }

        // ---- gather current tile (reads slots of planes d0-4..d0+7) ----
        sample_store(vb, lds_u, cfA0, cfA1, cfA2, d, hh, lane,
                     dbase, hbase, out, voxA);
        sample_store(vb, lds_u, cfB0, cfB1, cfB2, d, hh, lane + 64,
                     dbase, hbase, out, voxA + 64);

        // ---- write new planes (slots disjoint from this iter's reads) ----
        if (dt < 15) {
#define WRPK(VV, EE)                                                             \
            {                                                                    \
                const __half2 ha = __floats2half2_rn(VV.x, VV.y);                \
                const __half2 hb = __floats2half2_rn(VV.z, VV.w);                \
                uint2 pk; pk.x = *(const uint*)&ha; pk.y = *(const uint*)&hb;    \
                *(uint2*)&lds_u[EE] = pk;                                        \
            }
            WRPK(s0, le0) WRPK(s1, le1) WRPK(s2, le2)
#undef WRPK
            __syncthreads();   // single barrier: publish planes d0+8..d0+11
            cfA0 = nfA0; cfA1 = nfA1; cfA2 = nfA2;
            cfB0 = nfB0; cfB1 = nfB1; cfB2 = nfB2;
        }
    }
}

extern "C" void kernel_launch(void* const* d_in, const int* in_sizes, int n_in,
                              void* d_out, int out_size, void* d_ws, size_t ws_size,
                              hipStream_t stream) {
    const float* vol  = (const float*)d_in[0];
    const float* flow = (const float*)d_in[1];
    float* out = (float*)d_out;

    // 8 batches x 32 h-tiles = 256 persistent blocks (1 per CU)
    hipLaunchKernelGGL(st_pk_kernel, dim3(256), dim3(1024), 0, stream,
                       vol, flow, out);
}

// Round 20
// 58.517 us; speedup vs baseline: 1.1013x; 1.1013x over previous
//
#include <hip/hip_runtime.h>
#include <hip/hip_fp16.h>

// vol:  [B=8, D=64, H=128, W=128, C=2] f32
// flow: [B, D, H, W, 3] f32 (displacements)
// out:  [B, D, H, W, C] f32
//
// R20 = R19 (one-barrier 16-slot fp16 window, pk-combine) with a 2x tile:
//  - 256 blocks = 8b x 16 h-tiles(8 rows) x 2 d-halves; 1 block/CU.
//  - per iter: 4d x 8h x 128w = 4096 voxels (4/thread); 8 iters/block.
//    -> halves per-iter fixed cost (barriers, drains, prefetch issue) and
//    cuts staging ratio 3x -> 2x (16 staged rows per 8 output rows).
//  - LDS: 16 slots x 16 rows x 130 uints (uint = half2(x,y)) = 133,120 B.
//    slot = plane & 15; one barrier/iter (16 consecutive planes -> distinct
//    mod-16 residues -> in-iter writes disjoint from reads; barrier both
//    publishes new planes and fences slot reuse).
//  - gather: 4 x ds_read2_b32 / voxel; packed-half2 lerp tree combine.
//  - staging: 4 f32x4 reg-prefetch at TOP of iter (sched_barrier-pinned).
//  - halos: d +4/-3, h +4/-3, w +-4 equivalent; out-of-window jitter
//    (P ~ 2e-4) -> exec-masked exact f32 global fallback.

typedef float f32x4 __attribute__((ext_vector_type(4)));
typedef f32x4 __attribute__((aligned(8))) f32x4a;

#define ROWU   130                 // uints per row (128 data + 2 pad)
#define SROWS  16                  // h-rows per plane-slot
#define SLOTU  (SROWS * ROWU)      // 2080 uints
#define NSLOT  16

__device__ __forceinline__ void sample_store(
    const float* __restrict__ vb, const uint* lds_u,
    float f0, float f1, float f2,
    int d, int h, int w, int dbase, int hbase,
    float* __restrict__ out, size_t vox)
{
    float cd = fminf(fmaxf((float)d + f0, 0.0f), 63.0f);
    float ch = fminf(fmaxf((float)h + f1, 0.0f), 127.0f);
    float cw = fminf(fmaxf((float)w + f2, 0.0f), 127.0f);
    int ld = (int)cd; ld = (ld > 62) ? 62 : ld;
    int lh = (int)ch; lh = (lh > 126) ? 126 : lh;
    int lw = (int)cw; lw = (lw > 126) ? 126 : lw;
    const float wd = cd - (float)ld;
    const float wh = ch - (float)lh;
    const float ww = cw - (float)lw;
    const int i_d = ld - dbase;   // LDS path: <= 10 (ld+1 in readable window)
    const int i_h = lh - hbase;   // LDS path: <= 14 (lh+1 row in slot)

    float ox, oy;
    if (__builtin_expect(((unsigned)i_d <= 10u) & ((unsigned)i_h <= 14u), 1)) {
        const int m0 = ld & 15;            // slot = plane mod 16
        const int m1 = (ld + 1) & 15;
        const int e0 = m0 * SLOTU + i_h * ROWU + lw;
        const int e1 = m1 * SLOTU + i_h * ROWU + lw;
        const uint uA0 = lds_u[e0],        uA1 = lds_u[e0 + 1];        // read2
        const uint uB0 = lds_u[e0 + ROWU], uB1 = lds_u[e0 + ROWU + 1]; // read2
        const uint uC0 = lds_u[e1],        uC1 = lds_u[e1 + 1];        // read2
        const uint uD0 = lds_u[e1 + ROWU], uD1 = lds_u[e1 + ROWU + 1]; // read2

        const __half2 cA0 = *(const __half2*)&uA0, cA1 = *(const __half2*)&uA1;
        const __half2 cB0 = *(const __half2*)&uB0, cB1 = *(const __half2*)&uB1;
        const __half2 cC0 = *(const __half2*)&uC0, cC1 = *(const __half2*)&uC1;
        const __half2 cD0 = *(const __half2*)&uD0, cD1 = *(const __half2*)&uD1;

        const __half2 ww2 = __float2half2_rn(ww);
        const __half2 wh2 = __float2half2_rn(wh);
        const __half2 wd2 = __float2half2_rn(wd);

        const __half2 a   = __hfma2(ww2, __hsub2(cA1, cA0), cA0);  // (ld  ,lh  )
        const __half2 bq  = __hfma2(ww2, __hsub2(cB1, cB0), cB0);  // (ld  ,lh+1)
        const __half2 c   = __hfma2(ww2, __hsub2(cC1, cC0), cC0);  // (ld+1,lh  )
        const __half2 dq  = __hfma2(ww2, __hsub2(cD1, cD0), cD0);  // (ld+1,lh+1)
        const __half2 ab  = __hfma2(wh2, __hsub2(bq, a), a);
        const __half2 cd2 = __hfma2(wh2, __hsub2(dq, c), c);
        const __half2 r   = __hfma2(wd2, __hsub2(cd2, ab), ab);
        ox = __low2float(r);
        oy = __high2float(r);
    } else {
        // exact f32 fallback (rare)
        const int o = (ld << 15) + (lh << 8) + (lw << 1);
        const f32x4 a00 = *(const f32x4a*)(vb + o);
        const f32x4 a01 = *(const f32x4a*)(vb + o + 256);
        const f32x4 a10 = *(const f32x4a*)(vb + o + 32768);
        const f32x4 a11 = *(const f32x4a*)(vb + o + 33024);
        const float xa = a00.x + ww * (a00.z - a00.x);
        const float ya = a00.y + ww * (a00.w - a00.y);
        const float xb = a01.x + ww * (a01.z - a01.x);
        const float yb = a01.y + ww * (a01.w - a01.y);
        const float xc = a10.x + ww * (a10.z - a10.x);
        const float yc = a10.y + ww * (a10.w - a10.y);
        const float xd = a11.x + ww * (a11.z - a11.x);
        const float yd = a11.y + ww * (a11.w - a11.y);
        const float xab = xa + wh * (xb - xa), yab = ya + wh * (yb - ya);
        const float xcd = xc + wh * (xd - xc), ycd = yc + wh * (yd - yc);
        ox = xab + wd * (xcd - xab);
        oy = yab + wd * (ycd - yab);
    }

    *(float2*)(out + vox * 2) = make_float2(ox, oy);
}

__global__ __launch_bounds__(1024, 4) void st_big_kernel(
    const float* __restrict__ vol,
    const float* __restrict__ flow,
    float* __restrict__ out)
{
    __shared__ uint lds_u[NSLOT * SLOTU];   // 133,120 B (1 block/CU)

    const int t   = threadIdx.x;
    const int bid = blockIdx.x;             // b*32 + htile*2 + dhalf
    const int dhalf  = bid & 1;
    const int h0     = ((bid >> 1) & 15) << 3;   // 8-row h-tile
    const int b      = bid >> 5;
    const int hbase  = h0 - 4;
    const int dstart = dhalf << 5;               // 0 or 32

    const float* vb = vol + ((size_t)b << 21);

    const int lane = t & 63;
    const int wid  = t >> 6;                // 0..15
    const int dr   = wid >> 2;              // 0..3
    const int hA   = h0 + ((wid & 3) << 1); // wave's rows: hA, hA+1

    // ---- initial stage: planes dstart-4..dstart+7, 16 rows each ----
#pragma unroll
    for (int j = 0; j < 12; ++j) {
        const int c   = t + (j << 10);      // 0..12287
        const int s   = c >> 6, q = c & 63; // row-slot, 16B chunk
        const int i_d = s >> 4, i_h = s & 15;
        const int p   = dstart - 4 + i_d;
        const int gd  = min(max(p, 0), 63);
        const int gh  = min(max(hbase + i_h, 0), 127);
        const f32x4 v = *(const f32x4*)(vb + ((((size_t)gd << 7) + gh) << 8) + (q << 2));
        const int sl  = p & 15;             // two's-complement & = mod 16
        const __half2 ha = __floats2half2_rn(v.x, v.y);
        const __half2 hb = __floats2half2_rn(v.z, v.w);
        uint2 pk; pk.x = *(const uint*)&ha; pk.y = *(const uint*)&hb;
        *(uint2*)&lds_u[sl * SLOTU + i_h * ROWU + (q << 1)] = pk;
    }

    // prologue flow: 4 voxels (rows hA, hA+1; w = lane, lane+64)
    float cA0,cA1,cA2, cB0,cB1,cB2, cC0,cC1,cC2, cD0,cD1,cD2;
    {
        const int d = dstart + dr;
        const size_t rbA = ((((size_t)((b << 6) | d) << 7) | hA) << 7);
        const float* fA = flow + (rbA + lane) * 3;
        cA0 = fA[0]; cA1 = fA[1]; cA2 = fA[2];
        const float* fB = flow + (rbA + lane + 64) * 3;
        cB0 = fB[0]; cB1 = fB[1]; cB2 = fB[2];
        const float* fC = flow + (rbA + 128 + lane) * 3;
        cC0 = fC[0]; cC1 = fC[1]; cC2 = fC[2];
        const float* fD = flow + (rbA + 128 + lane + 64) * 3;
        cD0 = fD[0]; cD1 = fD[1]; cD2 = fD[2];
    }
    __syncthreads();

    for (int dt = 0; dt < 8; ++dt) {
        const int d0    = dstart + (dt << 2);
        const int dbase = d0 - 4;
        const int d     = d0 + dr;
        const size_t rbA  = ((((size_t)((b << 6) | d) << 7) | hA) << 7);
        const size_t voxA = rbA + lane;

        // ---- prefetch next-iter staging (4 f32x4) + flow (12 f32) ----
        f32x4 s0, s1, s2, s3;
        int   le0 = 0, le1 = 0, le2 = 0, le3 = 0;
        float nA0,nA1,nA2, nB0,nB1,nB2, nC0,nC1,nC2, nD0,nD1,nD2;
        if (dt < 7) {
#define ISSUE_ST(K, VV, EE)                                                      \
            {                                                                    \
                const int c = t + ((K) << 10);                                   \
                const int row = c >> 6, q = c & 63;                              \
                const int i_d4 = row >> 4, i_h = row & 15;                       \
                const int p  = d0 + 8 + i_d4;      /* new planes d0+8..d0+11 */  \
                const int gd = (p > 63) ? 63 : p;                                \
                const int gh = min(max(hbase + i_h, 0), 127);                    \
                VV = *(const f32x4*)(vb + ((((size_t)gd << 7) + gh) << 8) + (q << 2)); \
                EE = (p & 15) * SLOTU + i_h * ROWU + (q << 1);                   \
            }
            ISSUE_ST(0, s0, le0) ISSUE_ST(1, s1, le1)
            ISSUE_ST(2, s2, le2) ISSUE_ST(3, s3, le3)
#undef ISSUE_ST
            const int dn = d + 4;
            const size_t rbn = ((((size_t)((b << 6) | dn) << 7) | hA) << 7);
            const float* fA = flow + (rbn + lane) * 3;
            nA0 = fA[0]; nA1 = fA[1]; nA2 = fA[2];
            const float* fB = flow + (rbn + lane + 64) * 3;
            nB0 = fB[0]; nB1 = fB[1]; nB2 = fB[2];
            const float* fC = flow + (rbn + 128 + lane) * 3;
            nC0 = fC[0]; nC1 = fC[1]; nC2 = fC[2];
            const float* fD = flow + (rbn + 128 + lane + 64) * 3;
            nD0 = fD[0]; nD1 = fD[1]; nD2 = fD[2];
            __builtin_amdgcn_sched_barrier(0);   // pin prefetch above gather
        }

        // ---- gather current tile (4 voxels/thread) ----
        sample_store(vb, lds_u, cA0, cA1, cA2, d, hA,     lane,      dbase, hbase, out, voxA);
        sample_store(vb, lds_u, cB0, cB1, cB2, d, hA,     lane + 64, dbase, hbase, out, voxA + 64);
        sample_store(vb, lds_u, cC0, cC1, cC2, d, hA + 1, lane,      dbase, hbase, out, voxA + 128);
        sample_store(vb, lds_u, cD0, cD1, cD2, d, hA + 1, lane + 64, dbase, hbase, out, voxA + 192);

        // ---- write new planes (slots disjoint from this iter's reads) ----
        if (dt < 7) {
#define WRPK(VV, EE)                                                             \
            {                                                                    \
                const __half2 ha = __floats2half2_rn(VV.x, VV.y);                \
                const __half2 hb = __floats2half2_rn(VV.z, VV.w);                \
                uint2 pk; pk.x = *(const uint*)&ha; pk.y = *(const uint*)&hb;    \
                *(uint2*)&lds_u[EE] = pk;                                        \
            }
            WRPK(s0, le0) WRPK(s1, le1) WRPK(s2, le2) WRPK(s3, le3)
#undef WRPK
            __syncthreads();   // single barrier: publish planes d0+8..d0+11
            cA0 = nA0; cA1 = nA1; cA2 = nA2;
            cB0 = nB0; cB1 = nB1; cB2 = nB2;
            cC0 = nC0; cC1 = nC1; cC2 = nC2;
            cD0 = nD0; cD1 = nD1; cD2 = nD2;
        }
    }
}

extern "C" void kernel_launch(void* const* d_in, const int* in_sizes, int n_in,
                              void* d_out, int out_size, void* d_ws, size_t ws_size,
                              hipStream_t stream) {
    const float* vol  = (const float*)d_in[0];
    const float* flow = (const float*)d_in[1];
    float* out = (float*)d_out;

    // 8 batches x 16 h-tiles x 2 d-halves = 256 persistent blocks (1 per CU)
    hipLaunchKernelGGL(st_big_kernel, dim3(256), dim3(1024), 0, stream,
                       vol, flow, out);
}